// Round 1
// baseline (210.167 us; speedup 1.0000x reference)
//
#include <hip/hip_runtime.h>
#include <cstdint>

#define EPSN 1e-12f
static constexpr int B_ROWS = 1024;
static constexpr int IN_DIM = 512;
static constexpr int OUT_DIM = 64000;

typedef __attribute__((ext_vector_type(8))) short bf16x8;
typedef __attribute__((ext_vector_type(4))) float f32x4;

__device__ __forceinline__ unsigned short f2bf(float f) {
  uint32_t u = __builtin_bit_cast(uint32_t, f);
  u += 0x7fffu + ((u >> 16) & 1u);   // round-to-nearest-even
  return (unsigned short)(u >> 16);
}

__device__ __forceinline__ float wave_sum(float v) {
#pragma unroll
  for (int off = 32; off; off >>= 1) v += __shfl_xor(v, off);
  return v;
}

__device__ __forceinline__ void async16(const void* g, void* l) {
  __builtin_amdgcn_global_load_lds((const __attribute__((address_space(1))) uint32_t*)g,
                                   (__attribute__((address_space(3))) uint32_t*)l, 16, 0, 0);
}

// --- kernel 1: weight row L2-normalize; write wn (f32, output 1) + wn bf16 to ws ---
__global__ void wnorm_kernel(const float* __restrict__ Wg, float* __restrict__ wnOut,
                             unsigned short* __restrict__ wbf, int useBf) {
  int lane = threadIdx.x & 63;
  int row = blockIdx.x * 4 + (threadIdx.x >> 6);
  const float* src = Wg + (size_t)row * IN_DIM + lane * 8;
  float4 a = *(const float4*)src;
  float4 b = *(const float4*)(src + 4);
  float ss = a.x * a.x;
  ss = fmaf(a.y, a.y, ss); ss = fmaf(a.z, a.z, ss); ss = fmaf(a.w, a.w, ss);
  ss = fmaf(b.x, b.x, ss); ss = fmaf(b.y, b.y, ss); ss = fmaf(b.z, b.z, ss);
  ss = fmaf(b.w, b.w, ss);
  ss = wave_sum(ss);
  float inv = 1.0f / fmaxf(sqrtf(ss), EPSN);
  float4 wa, wb;
  wa.x = a.x * inv; wa.y = a.y * inv; wa.z = a.z * inv; wa.w = a.w * inv;
  wb.x = b.x * inv; wb.y = b.y * inv; wb.z = b.z * inv; wb.w = b.w * inv;
  float* dst = wnOut + (size_t)row * IN_DIM + lane * 8;
  *(float4*)dst = wa;
  *(float4*)(dst + 4) = wb;
  if (useBf) {
    uint4 u;
    u.x = (uint32_t)f2bf(wa.x) | ((uint32_t)f2bf(wa.y) << 16);
    u.y = (uint32_t)f2bf(wa.z) | ((uint32_t)f2bf(wa.w) << 16);
    u.z = (uint32_t)f2bf(wb.x) | ((uint32_t)f2bf(wb.y) << 16);
    u.w = (uint32_t)f2bf(wb.z) | ((uint32_t)f2bf(wb.w) << 16);
    *(uint4*)(wbf + (size_t)row * IN_DIM + lane * 8) = u;
  }
}

// --- kernel 2: x row norms (for epilogue) + raw-x bf16 cast to ws ---
__global__ void xprep_kernel(const float* __restrict__ X, float* __restrict__ norms,
                             unsigned short* __restrict__ xbf) {
  int lane = threadIdx.x & 63;
  int row = blockIdx.x * 4 + (threadIdx.x >> 6);
  const float* src = X + (size_t)row * IN_DIM + lane * 8;
  float4 a = *(const float4*)src;
  float4 b = *(const float4*)(src + 4);
  float ss = a.x * a.x;
  ss = fmaf(a.y, a.y, ss); ss = fmaf(a.z, a.z, ss); ss = fmaf(a.w, a.w, ss);
  ss = fmaf(b.x, b.x, ss); ss = fmaf(b.y, b.y, ss); ss = fmaf(b.z, b.z, ss);
  ss = fmaf(b.w, b.w, ss);
  ss = wave_sum(ss);
  if (lane == 0) norms[row] = sqrtf(ss);
  uint4 u;
  u.x = (uint32_t)f2bf(a.x) | ((uint32_t)f2bf(a.y) << 16);
  u.y = (uint32_t)f2bf(a.z) | ((uint32_t)f2bf(a.w) << 16);
  u.z = (uint32_t)f2bf(b.x) | ((uint32_t)f2bf(b.y) << 16);
  u.w = (uint32_t)f2bf(b.z) | ((uint32_t)f2bf(b.w) << 16);
  *(uint4*)(xbf + (size_t)row * IN_DIM + lane * 8) = u;
}

// --- kernel 3: exact f32 dot at (row, label[row]) — kills bf16 sign-flip at the
// reference's cosine==0 discontinuity on label entries ---
__global__ void labelfix_kernel(const float* __restrict__ X, const int* __restrict__ label,
                                const float* __restrict__ wn, float* __restrict__ fixdot) {
  int lane = threadIdx.x & 63;
  int row = blockIdx.x * 4 + (threadIdx.x >> 6);
  int lab = label[row];
  const float* xs = X + (size_t)row * IN_DIM + lane * 8;
  const float* wsrc = wn + (size_t)lab * IN_DIM + lane * 8;
  float4 xa = *(const float4*)xs, xb = *(const float4*)(xs + 4);
  float4 wa = *(const float4*)wsrc, wb = *(const float4*)(wsrc + 4);
  float d = xa.x * wa.x;
  d = fmaf(xa.y, wa.y, d); d = fmaf(xa.z, wa.z, d); d = fmaf(xa.w, wa.w, d);
  d = fmaf(xb.x, wb.x, d); d = fmaf(xb.y, wb.y, d); d = fmaf(xb.z, wb.z, d);
  d = fmaf(xb.w, wb.w, d);
  d = wave_sum(d);
  if (lane == 0) fixdot[row] = d;
}

// --- kernel 4: bf16 MFMA GEMM (M=1024,N=64000,K=512) + margin epilogue ---
// 128x128 tile, BK=32, 4 waves (2x2), each wave 4x4 frags of 16x16x32.
// LDS XOR-swizzle: byte ^= ((row>>1)&7)<<4 ; staged via global_load_lds with
// pre-swizzled GLOBAL source (LDS dest stays linear).
template <bool BF16B>
__global__ __launch_bounds__(256, 2) void gemm_epi_kernel(
    const unsigned short* __restrict__ Abf, const unsigned short* __restrict__ Bbf,
    const float* __restrict__ Bf32, const float* __restrict__ norms,
    const float* __restrict__ fixdot, const int* __restrict__ label,
    const float* __restrict__ mArr, float* __restrict__ out0) {
  __shared__ uint4 smem4[1024];  // 16 KiB: A tile [0,8192), B tile [8192,16384)
  char* smem = (char*)smem4;

  int t = threadIdx.x;
  // XCD-bijective swizzle: all 8 M-tiles of one B-panel on the same XCD.
  int flat = blockIdx.x;
  int xcd = flat & 7;
  int wk = (flat >> 3) + xcd * 500;   // 4000 = 8*500 exactly -> bijective
  int mT = wk & 7, nT = wk >> 3;
  int rowA0 = mT * 128, rowB0 = nT * 128;

  int lane = t & 63;
  int wm = (t >> 6) >> 1, wn2 = (t >> 6) & 1;
  int rl = lane & 15, sl = lane >> 4;

  f32x4 acc[4][4];
#pragma unroll
  for (int i = 0; i < 4; ++i)
#pragma unroll
    for (int j = 0; j < 4; ++j) acc[i][j] = (f32x4){0.f, 0.f, 0.f, 0.f};

  for (int kk = 0; kk < 16; ++kk) {
    int k0 = kk * 32;
#pragma unroll
    for (int c = 0; c < 2; ++c) {  // A tile: 8 KiB = 2 x (256 thr x 16 B)
      int W = (t + c * 256) * 16;
      int line = W >> 7;
      int xx = ((W >> 4) & 7) ^ (line & 7);
      int r = line * 2 + (xx >> 2), s = xx & 3;
      async16(Abf + (size_t)(rowA0 + r) * IN_DIM + k0 + s * 8, smem + W);
    }
    if constexpr (BF16B) {
#pragma unroll
      for (int c = 0; c < 2; ++c) {
        int W = (t + c * 256) * 16;
        int line = W >> 7;
        int xx = ((W >> 4) & 7) ^ (line & 7);
        int r = line * 2 + (xx >> 2), s = xx & 3;
        async16(Bbf + (size_t)(rowB0 + r) * IN_DIM + k0 + s * 8, smem + 8192 + W);
      }
    } else {  // fallback: read wn f32 from d_out, convert while staging
#pragma unroll
      for (int c = 0; c < 2; ++c) {
        int blk = t + c * 256;
        int r = blk >> 2, s = blk & 3;
        const float* srcp = Bf32 + (size_t)(rowB0 + r) * IN_DIM + k0 + s * 8;
        float4 f0 = *(const float4*)srcp;
        float4 f1 = *(const float4*)(srcp + 4);
        uint4 u;
        u.x = (uint32_t)f2bf(f0.x) | ((uint32_t)f2bf(f0.y) << 16);
        u.y = (uint32_t)f2bf(f0.z) | ((uint32_t)f2bf(f0.w) << 16);
        u.z = (uint32_t)f2bf(f1.x) | ((uint32_t)f2bf(f1.y) << 16);
        u.w = (uint32_t)f2bf(f1.z) | ((uint32_t)f2bf(f1.w) << 16);
        int off = 8192 + ((r * 64 + s * 16) ^ (((r >> 1) & 7) << 4));
        *(uint4*)(smem + off) = u;
      }
    }
    __syncthreads();
    bf16x8 av[4], bv[4];
#pragma unroll
    for (int i = 0; i < 4; ++i) {
      int r = wm * 64 + i * 16 + rl;
      av[i] = *(const bf16x8*)(smem + ((r * 64 + sl * 16) ^ (((r >> 1) & 7) << 4)));
    }
#pragma unroll
    for (int j = 0; j < 4; ++j) {
      int r = wn2 * 64 + j * 16 + rl;
      bv[j] = *(const bf16x8*)(smem + 8192 + ((r * 64 + sl * 16) ^ (((r >> 1) & 7) << 4)));
    }
#pragma unroll
    for (int i = 0; i < 4; ++i)
#pragma unroll
      for (int j = 0; j < 4; ++j)
        acc[i][j] = __builtin_amdgcn_mfma_f32_16x16x32_bf16(av[i], bv[j], acc[i][j], 0, 0, 0);
    __syncthreads();
  }

  // epilogue: out = dot, except at (r, label[r]) where the precise f32 dot decides
  float mm = mArr[0];
  float cm = cosf(mm), sm = sinf(mm);
  int rowb = rowA0 + wm * 64, colb = rowB0 + wn2 * 64;
#pragma unroll
  for (int i = 0; i < 4; ++i) {
    int lab4[4]; float n4[4], f4[4];
#pragma unroll
    for (int q = 0; q < 4; ++q) {
      int R = rowb + i * 16 + sl * 4 + q;
      lab4[q] = label[R];
      n4[q] = norms[R];
      f4[q] = fixdot[R];
    }
#pragma unroll
    for (int j = 0; j < 4; ++j) {
      int Cc = colb + j * 16 + rl;
      f32x4 v = acc[i][j];
#pragma unroll
      for (int q = 0; q < 4; ++q) {
        float val = v[q];
        if (Cc == lab4[q]) {
          float n = n4[q];
          float c = f4[q] / fmaxf(n, EPSN);
          val = (c > 0.f) ? n * (c * cm - sqrtf(fmaxf(1.f - c * c, 0.f)) * sm) : f4[q];
        }
        out0[(size_t)(rowb + i * 16 + sl * 4 + q) * OUT_DIM + Cc] = val;
      }
    }
  }
}

extern "C" void kernel_launch(void* const* d_in, const int* in_sizes, int n_in,
                              void* d_out, int out_size, void* d_ws, size_t ws_size,
                              hipStream_t stream) {
  const float* x = (const float*)d_in[0];
  const int* label = (const int*)d_in[1];
  const float* weight = (const float*)d_in[2];
  const float* mArr = (const float*)d_in[4];  // d_in[3] = s, unused by normfree output

  float* out0 = (float*)d_out;                               // [1024, 64000]
  float* wnOut = out0 + (size_t)B_ROWS * OUT_DIM;            // [64000, 512]

  char* ws = (char*)d_ws;
  float* norms = (float*)ws;                                 // 4 KiB
  float* fixdot = (float*)(ws + 4096);                       // 4 KiB
  unsigned short* xbf = (unsigned short*)(ws + 8192);        // 1 MiB
  unsigned short* wbf = (unsigned short*)(ws + 8192 + 2ull * B_ROWS * IN_DIM);
  size_t need = 8192 + 2ull * B_ROWS * IN_DIM + 2ull * OUT_DIM * IN_DIM;
  bool useBf = ws_size >= need;

  wnorm_kernel<<<OUT_DIM / 4, 256, 0, stream>>>(weight, wnOut, wbf, useBf ? 1 : 0);
  xprep_kernel<<<B_ROWS / 4, 256, 0, stream>>>(x, norms, xbf);
  labelfix_kernel<<<B_ROWS / 4, 256, 0, stream>>>(x, label, wnOut, fixdot);
  if (useBf)
    gemm_epi_kernel<true><<<4000, 256, 0, stream>>>(xbf, wbf, wnOut, norms, fixdot,
                                                    label, mArr, out0);
  else
    gemm_epi_kernel<false><<<4000, 256, 0, stream>>>(xbf, wbf, wnOut, norms, fixdot,
                                                     label, mArr, out0);
}